// Round 3
// baseline (30102.066 us; speedup 1.0000x reference)
//
#include <hip/hip_runtime.h>
#include <hip/hip_cooperative_groups.h>
#include <math.h>

namespace cg = cooperative_groups;

// MPGRUImputer on MI355X. B=8, F=1, N=1024, T=128, H=64, ORDER=2.
// PERSISTENT cooperative kernel: 256 blocks (1/CU) x 512 thr; each block owns
// (b, 32 nodes) for the whole T loop. h/u/direct-channels live in LDS; only
// diffusion hi-channels ([8][80][1024] bf16) cross blocks via global, with
// grid.sync() between phases. Inner MFMA loops identical to R2 (fat 5x2
// diffusion tile + K-split across 2 waves/SIMD, f32 reduce via LDS scratch).

typedef unsigned short u16;
typedef unsigned int u32;
typedef short bf16x8 __attribute__((ext_vector_type(8)));  // 8 bf16 = 4 VGPRs
typedef float f32x4 __attribute__((ext_vector_type(4)));

#define MFMA16(a, b, c) __builtin_amdgcn_mfma_f32_16x16x32_bf16((a), (b), (c), 0, 0, 0)

#define Bz 8
#define Tt 128
#define KC 416   // conv K (weight row stride): 66 hi + 66 lo + 4*66 z + 20 pad
#define KL 424   // LDS conv-B row stride in u16
#define DP 80    // global diffusion operand rows: 0..65 hi + 14 zero pad
#define ZLB (32 * KL * 2)        // 27136 B  zl[32][424] u16
#define SCRB (4 * 64 * 44 * 4)   // 45056 B  f32 K-split scratch
#define HFB (64 * 33 * 4)        // 8448 B   hf / uf each
#define SMEMB (ZLB + SCRB + 2 * HFB + 272)  // 89360 B

static __device__ __forceinline__ u16 f2b(float f) {  // RNE f32->bf16
  u32 u = __float_as_uint(f);
  u = (u + 0x7FFFu + ((u >> 16) & 1u)) >> 16;
  return (u16)u;
}
static __device__ __forceinline__ float b2f(u16 s) { return __uint_as_float(((u32)s) << 16); }
static __device__ __forceinline__ bf16x8 ld8(const u16* p) { return *reinterpret_cast<const bf16x8*>(p); }
static __device__ __forceinline__ void st2f(u16* p, float a, float b) {
  *reinterpret_cast<u32*>(p) = (u32)f2b(a) | ((u32)f2b(b) << 16);
}
static __device__ __forceinline__ void st2u(u16* p, u16 a, u16 b) {
  *reinterpret_cast<u32*>(p) = (u32)a | ((u32)b << 16);
}
static __device__ __forceinline__ float sigm(float x) { return 1.f / (1.f + __expf(-x)); }
static __device__ __forceinline__ float tanh_f(float x) {
  x = fminf(fmaxf(x, -15.f), 15.f);
  float e = __expf(2.f * x);
  return (e - 1.f) / (e + 1.f);
}

// ---- setup: row/col sums of adj -> 1/(sum+eps) ------------------------------
__global__ __launch_bounds__(256) void ksums(const float* adj, float* rinv, float* cinv) {
  int id = blockIdx.x * 256 + threadIdx.x;  // 0..2047
  if (id < 1024) {
    int w = id;
    float s = 0.f;
    for (int v = 0; v < 1024; ++v) s += adj[v * 1024 + w];
    cinv[w] = 1.f / (s + 1e-8f);
  } else {
    int w = id - 1024;
    float s = 0.f;
    for (int v = 0; v < 1024; ++v) s += adj[w * 1024 + v];
    rinv[w] = 1.f / (s + 1e-8f);
  }
}

// ---- setup: build bf16 operators A_f, A_b (+ transposed copies for A^2 GEMM)
__global__ __launch_bounds__(256) void kmakeops(const float* adj, const float* rinv, const float* cinv,
                                                u16* Aops, u16* supft, u16* supbt) {
  int idx = blockIdx.x * 256 + threadIdx.x;
  int w = idx >> 10, v = idx & 1023;
  float a = adj[idx];
  u16 f = f2b(a * rinv[w]);   // A_f[w][v]
  u16 bb = f2b(a * cinv[v]);  // = A_b[v][w]
  Aops[idx] = f;
  supft[v * 1024 + w] = f;
  supbt[idx] = bb;
  Aops[2 * 1048576 + v * 1024 + w] = bb;
}

// ---- setup: A^2 via bf16 MFMA ----------------------------------------------
__global__ __launch_bounds__(256) void kA2(u16* Aops, const u16* supft, const u16* supbt) {
  int wg = blockIdx.x;  // 128
  int o2 = wg & 1, mt = (wg >> 1) & 7, ntt = (wg >> 4) & 7;
  const u16* Ab = Aops + (o2 ? 2 * 1048576 : 0);
  const u16* Bb = o2 ? supbt : supft;
  u16* Ob = Aops + (o2 ? 3 * 1048576 : 1048576);
  int tid = threadIdx.x, wave = tid >> 6, lane = tid & 63, l15 = lane & 15, quad = lane >> 4;
  int mbase = mt * 128 + wave * 32;
  f32x4 acc[2][8];
#pragma unroll
  for (int m = 0; m < 2; ++m)
#pragma unroll
    for (int j = 0; j < 8; ++j) acc[m][j] = (f32x4){0.f, 0.f, 0.f, 0.f};
  for (int k = 0; k < 1024; k += 32) {
    int kq = k + quad * 8;
    bf16x8 av[2], bv[8];
#pragma unroll
    for (int m = 0; m < 2; ++m) av[m] = ld8(Ab + (mbase + m * 16 + l15) * 1024 + kq);
#pragma unroll
    for (int j = 0; j < 8; ++j) bv[j] = ld8(Bb + (ntt * 128 + j * 16 + l15) * 1024 + kq);
#pragma unroll
    for (int m = 0; m < 2; ++m)
#pragma unroll
      for (int j = 0; j < 8; ++j) acc[m][j] = MFMA16(av[m], bv[j], acc[m][j]);
  }
#pragma unroll
  for (int m = 0; m < 2; ++m)
#pragma unroll
    for (int j = 0; j < 8; ++j) {
      int v = ntt * 128 + j * 16 + l15;
#pragma unroll
      for (int i = 0; i < 4; ++i) {
        int w = mbase + m * 16 + quad * 4 + i;
        Ob[w * 1024 + v] = f2b(acc[m][j][i]);
      }
    }
}

// ---- setup: pack weights to bf16, K=416 layout ------------------------------
__global__ __launch_bounds__(256) void kpackw(const float* Wr, const float* Wu, const float* Wc,
                                              u16* Wrup, u16* Wcp) {
  int idx = blockIdx.x * 256 + threadIdx.x;
  int r = idx / KC, k = idx % KC;
  if (r >= 192) return;
  float wv = 0.f;
  if (k < 396) {
    int c = (k < 66) ? k : (k - 66);
    if (r < 64) wv = Wr[r * 330 + c];
    else if (r < 128) wv = Wu[(r - 64) * 330 + c];
    else wv = Wc[(r - 128) * 330 + c];
  }
  if (r < 128) Wrup[r * KC + k] = f2b(wv);
  else Wcp[(r - 128) * KC + k] = f2b(wv);
}

// ---- persistent main kernel -------------------------------------------------
__global__ __launch_bounds__(512, 1) void kmain(
    const float* __restrict__ x, const int* __restrict__ mask,
    const u16* __restrict__ Aops, const u16* __restrict__ Wrup, const u16* __restrict__ Wcp,
    const float* __restrict__ br, const float* __restrict__ bu, const float* __restrict__ bc,
    const float* __restrict__ Wout, const float* __restrict__ bout,
    float* __restrict__ preds, float* __restrict__ states,
    u16* __restrict__ xhg, u16* __restrict__ xcg) {
  extern __shared__ char smem[];
  u16 (*zl)[KL] = (u16(*)[KL])smem;                      // [32][424] conv B operand
  float* scr = (float*)(smem + ZLB);                     // [4][64][44] f32 K-split scratch
  float* hf = (float*)(smem + ZLB + SCRB);               // [64][33] h (f32, persistent)
  float* uf = (float*)(smem + ZLB + SCRB + HFB);         // [64][33] u gate
  float* wsh = (float*)(smem + ZLB + SCRB + 2 * HFB);    // [65]: Wout[64], bout

  cg::grid_group grid = cg::this_grid();
  int wg = blockIdx.x;
  int b = wg >> 5, nt = wg & 31, n0 = nt * 32;
  int tid = threadIdx.x, w = tid >> 6, lane = tid & 63, l15 = lane & 15, quad = lane >> 4;
  int op = w & 3, kh = w >> 2;

  // ---- prologue: zero LDS state, init t=0 ----
  for (int i = tid; i < 6784; i += 512) ((u32*)smem)[i] = 0;  // zl (incl. pads)
  for (int i = tid; i < 4224; i += 512) hf[i] = 0.f;          // hf + uf (contiguous)
  if (tid < 64) wsh[tid] = Wout[tid];
  if (tid == 64) wsh[64] = bout[0];
  for (int i = tid; i < 1280; i += 512) {  // zero own columns of xhg/xcg (rows 0..79)
    int row = i >> 4, cp = i & 15;
    int a = (b * DP + row) * 1024 + n0 + cp * 2;
    *(u32*)(xhg + a) = 0;
    *(u32*)(xcg + a) = 0;
  }
  for (int i = tid; i < 2048; i += 512) {  // states[t=0] = 0 for own nodes
    int o = i >> 5, nn = i & 31;
    states[(size_t)((b * 64 + o) * 1024 + n0 + nn) * 128] = 0.f;
  }
  __syncthreads();
  if (tid < 32) {  // x_in(t=0)
    int nn = n0 + tid;
    int xi = (b * 1024 + nn) * 128;
    float xhat = wsh[64];  // Wout . 0 + bout
    int mv = mask[xi];
    float xin = mv ? x[xi] : xhat;
    preds[xi] = xhat;
    u16 hi = f2b(xin), lo = f2b(xin - b2f(hi)), mb = f2b((float)mv);
    zl[tid][0] = hi; zl[tid][1] = mb; zl[tid][66] = lo;
    xhg[(b * DP + 0) * 1024 + nn] = hi;
    xhg[(b * DP + 1) * 1024 + nn] = mb;
    xcg[(b * DP + 0) * 1024 + nn] = hi;
    xcg[(b * DP + 1) * 1024 + nn] = mb;
  }
  __threadfence();
  grid.sync();

  // ---- T loop (step 127 provably affects no output -> 127 iterations) ----
  for (int t = 0; t < Tt - 1; ++t) {
    int t1 = t + 1;
    // ================= phase A =================
    {
      // diffusion of xh: out[ch][n] = sum_v xh[ch][v] * A_op[n][v]
      f32x4 dacc[5][2];
#pragma unroll
      for (int m = 0; m < 5; ++m)
#pragma unroll
        for (int j = 0; j < 2; ++j) dacc[m][j] = (f32x4){0.f, 0.f, 0.f, 0.f};
      {
        const u16* Zb = xhg + b * DP * 1024;
        const u16* Ab = Aops + (op << 20);
        int kbase = kh << 9;
        for (int k = 0; k < 512; k += 32) {
          int kq = kbase + k + quad * 8;
          bf16x8 av[5], bv[2];
#pragma unroll
          for (int m = 0; m < 5; ++m) av[m] = ld8(Zb + (m * 16 + l15) * 1024 + kq);
#pragma unroll
          for (int j = 0; j < 2; ++j) bv[j] = ld8(Ab + (n0 + j * 16 + l15) * 1024 + kq);
#pragma unroll
          for (int m = 0; m < 5; ++m)
#pragma unroll
            for (int j = 0; j < 2; ++j) dacc[m][j] = MFMA16(av[m], bv[j], dacc[m][j]);
        }
      }
      if (kh) {
        f32x4* s = (f32x4*)(scr + (op * 64 + lane) * 44);
#pragma unroll
        for (int m = 0; m < 5; ++m)
#pragma unroll
          for (int j = 0; j < 2; ++j) s[m * 2 + j] = dacc[m][j];
      }
      __syncthreads();  // B1
      if (!kh) {
        f32x4* s = (f32x4*)(scr + (op * 64 + lane) * 44);
        int cbase = 132 + op * 66;
#pragma unroll
        for (int m = 0; m < 5; ++m)
#pragma unroll
          for (int j = 0; j < 2; ++j) {
            f32x4 a = dacc[m][j] + s[m * 2 + j];
            u16* orow = zl[j * 16 + l15] + cbase;
            int c0 = m * 16 + quad * 4;
            if (c0 < 64) {
              st2f(orow + c0, a[0], a[1]);
              st2f(orow + c0 + 2, a[2], a[3]);
            } else if (c0 == 64) {
              st2f(orow + 64, a[0], a[1]);
            }
          }
      }
      __syncthreads();  // B2: zl complete

      // conv r,u: [128 out x 416] x [32 nodes]
      int og = op, obase = og * 32;
      f32x4 cacc[2][2];
#pragma unroll
      for (int m = 0; m < 2; ++m)
#pragma unroll
        for (int j = 0; j < 2; ++j) cacc[m][j] = (f32x4){0.f, 0.f, 0.f, 0.f};
      {
        int k0 = kh ? 224 : 0, k1 = kh ? KC : 224;
        for (int k = k0; k < k1; k += 32) {
          int kq = k + quad * 8;
          bf16x8 av[2], bv[2];
#pragma unroll
          for (int m = 0; m < 2; ++m) av[m] = ld8(Wrup + (obase + m * 16 + l15) * KC + kq);
#pragma unroll
          for (int j = 0; j < 2; ++j) bv[j] = ld8(zl[j * 16 + l15] + kq);
#pragma unroll
          for (int m = 0; m < 2; ++m)
#pragma unroll
            for (int j = 0; j < 2; ++j) cacc[m][j] = MFMA16(av[m], bv[j], cacc[m][j]);
        }
      }
      if (kh) {
        f32x4* s = (f32x4*)(scr + (og * 64 + lane) * 44);
#pragma unroll
        for (int m = 0; m < 2; ++m)
#pragma unroll
          for (int j = 0; j < 2; ++j) s[m * 2 + j] = cacc[m][j];
      }
      __syncthreads();  // B3 (all conv reads of zl h-channels done)
      if (!kh) {
        f32x4* s = (f32x4*)(scr + (og * 64 + lane) * 44);
#pragma unroll
        for (int m = 0; m < 2; ++m)
#pragma unroll
          for (int j = 0; j < 2; ++j) {
            f32x4 a = cacc[m][j] + s[m * 2 + j];
            int o0 = obase + m * 16 + quad * 4;
            int nl = j * 16 + l15, n = n0 + nl;
            if (o0 < 64) {  // r gate -> r*h into zl (local) + xcg hi (global)
              u16 hi4[4], lo4[4];
#pragma unroll
              for (int i = 0; i < 4; ++i) {
                float sg = sigm(a[i] + br[o0 + i]);
                float rh = sg * hf[(o0 + i) * 33 + nl];
                hi4[i] = f2b(rh);
                lo4[i] = f2b(rh - b2f(hi4[i]));
                xcg[(b * DP + 2 + o0 + i) * 1024 + n] = hi4[i];
              }
              st2u(&zl[nl][2 + o0], hi4[0], hi4[1]);
              st2u(&zl[nl][4 + o0], hi4[2], hi4[3]);
              st2u(&zl[nl][68 + o0], lo4[0], lo4[1]);
              st2u(&zl[nl][70 + o0], lo4[2], lo4[3]);
            } else {  // u gate -> LDS
#pragma unroll
              for (int i = 0; i < 4; ++i)
                uf[(o0 - 64 + i) * 33 + nl] = sigm(a[i] + bu[o0 - 64 + i]);
            }
          }
      }
      __threadfence();
      grid.sync();  // S1: xcg hi visible to all blocks
    }
    // ================= phase B =================
    {
      f32x4 dacc[5][2];
#pragma unroll
      for (int m = 0; m < 5; ++m)
#pragma unroll
        for (int j = 0; j < 2; ++j) dacc[m][j] = (f32x4){0.f, 0.f, 0.f, 0.f};
      {
        const u16* Zb = xcg + b * DP * 1024;
        const u16* Ab = Aops + (op << 20);
        int kbase = kh << 9;
        for (int k = 0; k < 512; k += 32) {
          int kq = kbase + k + quad * 8;
          bf16x8 av[5], bv[2];
#pragma unroll
          for (int m = 0; m < 5; ++m) av[m] = ld8(Zb + (m * 16 + l15) * 1024 + kq);
#pragma unroll
          for (int j = 0; j < 2; ++j) bv[j] = ld8(Ab + (n0 + j * 16 + l15) * 1024 + kq);
#pragma unroll
          for (int m = 0; m < 5; ++m)
#pragma unroll
            for (int j = 0; j < 2; ++j) dacc[m][j] = MFMA16(av[m], bv[j], dacc[m][j]);
        }
      }
      if (kh) {
        f32x4* s = (f32x4*)(scr + (op * 64 + lane) * 44);
#pragma unroll
        for (int m = 0; m < 5; ++m)
#pragma unroll
          for (int j = 0; j < 2; ++j) s[m * 2 + j] = dacc[m][j];
      }
      __syncthreads();  // B4
      if (!kh) {
        f32x4* s = (f32x4*)(scr + (op * 64 + lane) * 44);
        int cbase = 132 + op * 66;
#pragma unroll
        for (int m = 0; m < 5; ++m)
#pragma unroll
          for (int j = 0; j < 2; ++j) {
            f32x4 a = dacc[m][j] + s[m * 2 + j];
            u16* orow = zl[j * 16 + l15] + cbase;
            int c0 = m * 16 + quad * 4;
            if (c0 < 64) {
              st2f(orow + c0, a[0], a[1]);
              st2f(orow + c0 + 2, a[2], a[3]);
            } else if (c0 == 64) {
              st2f(orow + 64, a[0], a[1]);
            }
          }
      }
      __syncthreads();  // B5

      // conv c: [64 out x 416] x [32 nodes]
      int og = w & 1, jg = (w >> 1) & 1, task = w & 3;
      int obase = og * 32;
      f32x4 cacc[2];
      cacc[0] = (f32x4){0.f, 0.f, 0.f, 0.f};
      cacc[1] = (f32x4){0.f, 0.f, 0.f, 0.f};
      {
        int k0 = kh ? 224 : 0, k1 = kh ? KC : 224;
        for (int k = k0; k < k1; k += 32) {
          int kq = k + quad * 8;
          bf16x8 bv = ld8(zl[jg * 16 + l15] + kq);
          bf16x8 av0 = ld8(Wcp + (obase + l15) * KC + kq);
          bf16x8 av1 = ld8(Wcp + (obase + 16 + l15) * KC + kq);
          cacc[0] = MFMA16(av0, bv, cacc[0]);
          cacc[1] = MFMA16(av1, bv, cacc[1]);
        }
      }
      if (kh) {
        f32x4* s = (f32x4*)(scr + (task * 64 + lane) * 44);
        s[0] = cacc[0];
        s[1] = cacc[1];
      }
      __syncthreads();  // B6 (conv reads of zl rh-channels done)
      if (!kh) {  // reduce + h update
        f32x4* s = (f32x4*)(scr + (task * 64 + lane) * 44);
        int nl = jg * 16 + l15, n = n0 + nl;
#pragma unroll
        for (int m = 0; m < 2; ++m) {
          f32x4 a = cacc[m] + s[m];
          int o0 = obase + m * 16 + quad * 4;
          u16 hi4[4], lo4[4];
#pragma unroll
          for (int i = 0; i < 4; ++i) {
            int o = o0 + i;
            float c = tanh_f(a[i] + bc[o]);
            float u = uf[o * 33 + nl], hp = hf[o * 33 + nl];
            float hn = u * hp + (1.f - u) * c;
            hf[o * 33 + nl] = hn;
            hi4[i] = f2b(hn);
            lo4[i] = f2b(hn - b2f(hi4[i]));
            states[(size_t)((b * 64 + o) * 1024 + n) * 128 + t1] = hn;
            xhg[(b * DP + 2 + o) * 1024 + n] = hi4[i];
          }
          st2u(&zl[nl][2 + o0], hi4[0], hi4[1]);
          st2u(&zl[nl][4 + o0], hi4[2], hi4[3]);
          st2u(&zl[nl][68 + o0], lo4[0], lo4[1]);
          st2u(&zl[nl][70 + o0], lo4[2], lo4[3]);
        }
      }
      __syncthreads();  // B7: hf updated
      if (tid < 32) {  // x_hat -> preds, x_in(t+1) -> zl + xhg/xcg rows 0,1
        int nn = n0 + tid;
        float xhat = wsh[64];
#pragma unroll
        for (int o = 0; o < 64; ++o) xhat += wsh[o] * hf[o * 33 + tid];
        int xi = (b * 1024 + nn) * 128 + t1;
        int mv = mask[xi];
        float xin = mv ? x[xi] : xhat;
        preds[xi] = xhat;
        u16 hi2 = f2b(xin), lo2 = f2b(xin - b2f(hi2)), mb = f2b((float)mv);
        zl[tid][0] = hi2; zl[tid][1] = mb; zl[tid][66] = lo2;
        xhg[(b * DP + 0) * 1024 + nn] = hi2;
        xhg[(b * DP + 1) * 1024 + nn] = mb;
        xcg[(b * DP + 0) * 1024 + nn] = hi2;
        xcg[(b * DP + 1) * 1024 + nn] = mb;
      }
      __threadfence();
      grid.sync();  // S2: xhg visible for next step
    }
  }
}

extern "C" void kernel_launch(void* const* d_in, const int* in_sizes, int n_in,
                              void* d_out, int out_size, void* d_ws, size_t ws_size,
                              hipStream_t stream) {
  const float* x = (const float*)d_in[0];
  const int* mask = (const int*)d_in[1];
  const float* adj = (const float*)d_in[2];
  const float* Wr = (const float*)d_in[3];
  const float* br = (const float*)d_in[4];
  const float* Wu = (const float*)d_in[5];
  const float* bu = (const float*)d_in[6];
  const float* Wc = (const float*)d_in[7];
  const float* bc = (const float*)d_in[8];
  const float* Wout = (const float*)d_in[9];
  const float* bout = (const float*)d_in[10];

  float* preds = (float*)d_out;                  // [8,1,1024,128]
  float* states = preds + 8 * 1024 * 128;        // [1,8,64,1024,128]

  // workspace carve-up
  u16* Aops = (u16*)d_ws;                        // [4][1024][1024]
  u16* supft = Aops + 4 * 1048576;               // A_f^T
  u16* supbt = supft + 1048576;                  // A_b^T
  float* rinv = (float*)(supbt + 1048576);
  float* cinv = rinv + 1024;
  u16* xhg = (u16*)(cinv + 1024);                // [8][80][1024] phase-A operand (hi)
  u16* xcg = xhg + Bz * DP * 1024;               // [8][80][1024] phase-B operand (hi)
  u16* Wrup = xcg + Bz * DP * 1024;              // [128][416]
  u16* Wcp = Wrup + 128 * KC;                    // [64][416]

  static int lds_set = 0;
  if (!lds_set) {  // allow >64KB dynamic LDS (gfx950 has 160KB/CU)
    hipFuncSetAttribute((const void*)kmain, hipFuncAttributeMaxDynamicSharedMemorySize, SMEMB);
    lds_set = 1;
  }

  ksums<<<8, 256, 0, stream>>>(adj, rinv, cinv);
  kmakeops<<<4096, 256, 0, stream>>>(adj, rinv, cinv, Aops, supft, supbt);
  kA2<<<128, 256, 0, stream>>>(Aops, supft, supbt);
  kpackw<<<312, 256, 0, stream>>>(Wr, Wu, Wc, Wrup, Wcp);

  void* args[] = {(void*)&x, (void*)&mask, (void*)&Aops, (void*)&Wrup, (void*)&Wcp,
                  (void*)&br, (void*)&bu, (void*)&bc, (void*)&Wout, (void*)&bout,
                  (void*)&preds, (void*)&states, (void*)&xhg, (void*)&xcg};
  hipLaunchCooperativeKernel((void*)kmain, dim3(256), dim3(512), args, SMEMB, stream);
}